// Round 11
// baseline (317.569 us; speedup 1.0000x reference)
//
#include <hip/hip_runtime.h>

// ---------------------------------------------------------------------------
// DiffAttention forward, bf16 MFMA pipeline.  B=4 T=1024 C=1024 H=16 hs=64 dv=128.
//   1. prep_kernel (FUSED: cast x->bf16 + all 4 weight transpose-casts) —
//      one launch, grid-range dispatch.  Lambda folded into combine.
//   2. proj GEMM: R4 gemm256 (256x256, BK=64, 8 waves, 4-phase, T2 swizzle,
//      vmcnt(0) boundary) — best MEASURED proj (~72us, reproduced R4+R8).
//   3. transpose v slice -> vt[(b,h)][dim][token] (plain, R3)
//   4. attention: split-stream, UNPAIRED LPT grid 2048 (exact R3 kernel,
//      74.7-76.3us measured) -> a_s = (P/l)V fp16.
//   4b. combine: per-wave lambda dot (fused), y = a1 - lam_h*a2, subLN(128),
//      *(1-LI), bf16 -> yln.
//   5. out GEMM: gemm_bt BN=128 (256 blocks = 1 round).
// Launches: 10 -> 6 (R18: ~100us of wall time was unaccounted by kernel-time
// bottom-up => inter-dispatch gaps; prep fusion attacks it at ~zero risk).
// MFMA mappings (HW-verified): A[m=lane&15][k=quad*8+j] (K=32) / quad*4+j
// (K=16); B^T[n=lane&15][k=same]; C/D: col=lane&15, row=quad*4+reg.
// R8: #else of MFMA16 guard must be host-safe.
// R10 (R2): no-LDS direct-global attn regressed. Keep LDS staging.
// R13 (R5): 1-blk/CU grids pay round-tails; 384-tile proj grid unavoidable.
// R14 (R6): wave-tile LDS economics: mt*nt/(mt+nt) >= ~2.5. Keep 128x64.
// R16: infra failures -> resubmit identical, don't mutate blind.
// R17 (R8): attn bank conflicts NOT critical path; VGPR/occupancy is.
// R18 (R9): counted-vmcnt ring proj ~5us SLOWER than R4 4-phase — second
// null for T4-alone on this structure. proj FROZEN at R4 4-phase.
// R19 (this round): R10 was an infra failure (container died twice, same as
// R7) — resubmitting the identical R10 kernel; predictions remain untested.
// ---------------------------------------------------------------------------

#define T_SEQ 1024
#define NH 16
#define DV 128
#define NPROJ 6144
#define KSTR 72  // attn K/V LDS row stride (elements)

typedef __bf16 bf16_t;
typedef __bf16 bf16x8 __attribute__((ext_vector_type(8)));
typedef __bf16 bf16x4 __attribute__((ext_vector_type(4)));
typedef __bf16 bf16x2 __attribute__((ext_vector_type(2)));
typedef _Float16 f16x4 __attribute__((ext_vector_type(4)));
typedef _Float16 f16x2 __attribute__((ext_vector_type(2)));
typedef short s16x4 __attribute__((ext_vector_type(4)));
typedef float f32x4 __attribute__((ext_vector_type(4)));

#define LAMBDA_INIT 0.35550906759096928f
#define ONE_MINUS_LI 0.6444909324090307f
#define LOG2E 1.4426950408889634f
// defer-rescale threshold in RAW score units: 8 / (0.125*log2e) ~= 44.36
#define RTHR 44.36f

#if __has_builtin(__builtin_amdgcn_mfma_f32_16x16x16_bf16)
#define MFMA16(a, b, c) __builtin_amdgcn_mfma_f32_16x16x16_bf16(a, b, c, 0, 0, 0)
#elif __has_builtin(__builtin_amdgcn_mfma_f32_16x16x16bf16_1k)
#define MFMA16(a, b, c)                                                       \
  __builtin_amdgcn_mfma_f32_16x16x16bf16_1k(                                  \
      __builtin_bit_cast(s16x4, a), __builtin_bit_cast(s16x4, b), c, 0, 0, 0)
#else
#define MFMA16(a, b, c) (c)  // host pass only — never executed
#endif

#define MFMA32(a, b, c) __builtin_amdgcn_mfma_f32_16x16x32_bf16(a, b, c, 0, 0, 0)

// async global->LDS, 16B/lane.
#define GLDS(g, l)                                                            \
  __builtin_amdgcn_global_load_lds(                                           \
      (const __attribute__((address_space(1))) void*)(g),                     \
      (__attribute__((address_space(3))) void*)(l), 16, 0, 0)

// ---------------- workspace layout (bytes) ----------------
static const size_t OFF_WCAT = 0;                                  // 6144x1024 bf16
static const size_t OFF_XB = OFF_WCAT + (size_t)6144 * 1024 * 2;   // 4096x1024 bf16
static const size_t OFF_WCT = OFF_XB + (size_t)4096 * 1024 * 2;    // 1024x2048 bf16
static const size_t OFF_PROJ = OFF_WCT + (size_t)2048 * 1024 * 2;  // 4096x6144 bf16
static const size_t OFF_VT = OFF_PROJ + (size_t)4096 * 6144 * 2;   // 64*128*1024 bf16
static const size_t OFF_YLN = OFF_VT + (size_t)64 * 128 * 1024 * 2;// 4096x2048 bf16
// a1 (fp16, 16.78 MB) aliases YLN (combine rewrites in place); a2 aliases
// WCAT+XB (dead after proj GEMM).

// ---------------- FUSED prep: cast_x + 4 weight transpose-casts -------------
// grid 12288 x 256:
//   [0,4096)      cast_x          (x -> xb)
//   [4096,8192)   Wq1/Wq2/Wk1/Wk2 -> wcat rows z*1024..  (z = (b-4096)>>10)
//   [8192,10240)  Wv -> wcat rows 4096.. (K=1024, N=2048)
//   [10240,12288) Wc -> wct       (K=2048, N=1024)
__global__ void __launch_bounds__(256) prep_kernel(
    const float* __restrict__ x, const float* __restrict__ Wq1,
    const float* __restrict__ Wq2, const float* __restrict__ Wk1,
    const float* __restrict__ Wk2, const float* __restrict__ Wv,
    const float* __restrict__ Wc, bf16_t* __restrict__ xb,
    bf16_t* __restrict__ wcat, bf16_t* __restrict__ wct) {
  __shared__ float tile[32][33];
  const int b = blockIdx.x;
  if (b < 4096) {
    const int i = (b * 256 + threadIdx.x) * 4;
    float4 v = *(const float4*)(x + i);
    bf16x4 r = {(bf16_t)v.x, (bf16_t)v.y, (bf16_t)v.z, (bf16_t)v.w};
    *(bf16x4*)(xb + i) = r;
    return;
  }
  const float* W;
  bf16_t* Wt;
  int K, N, row0, k0, n0;
  if (b < 8192) {
    int idx = b - 4096;
    const int z = idx >> 10;
    idx &= 1023;
    const float* Ws[4] = {Wq1, Wq2, Wk1, Wk2};
    W = Ws[z];
    Wt = wcat;
    K = 1024;
    N = 1024;
    row0 = z * 1024;
    k0 = (idx & 31) * 32;
    n0 = (idx >> 5) * 32;
  } else if (b < 10240) {
    const int idx = b - 8192;
    W = Wv;
    Wt = wcat;
    K = 1024;
    N = 2048;
    row0 = 4096;
    k0 = (idx & 31) * 32;
    n0 = (idx >> 5) * 32;
  } else {
    const int idx = b - 10240;
    W = Wc;
    Wt = wct;
    K = 2048;
    N = 1024;
    row0 = 0;
    k0 = (idx & 63) * 32;
    n0 = (idx >> 6) * 32;
  }
  const int tx = threadIdx.x & 31, ty = threadIdx.x >> 5;  // 32x8
#pragma unroll
  for (int i = 0; i < 32; i += 8)
    tile[ty + i][tx] = W[(long)(k0 + ty + i) * N + n0 + tx];
  __syncthreads();
#pragma unroll
  for (int i = 0; i < 32; i += 8)
    Wt[(long)(row0 + n0 + ty + i) * K + k0 + tx] = (bf16_t)tile[tx][ty + i];
}

// ---------------- proj GEMM: R4 256x256 4-phase (measured-best, FROZEN) -----
// C[M][N] bf16 = A[M][K] @ Bt[N][K]^T.  grid.x = (M/256)*(N/256), %8 == 0.
// LDS: 2 K-tile buffers (A 256x64 + B 256x64 each) = 128 KiB.  Staging for
// tile t+1 goes into buf^1, issued in phases 0-1, drained by ONE vmcnt(0)+
// barrier at the tile boundary.  T2 swizzle: LDS granule g of row r holds
// global granule g^(r&7); reads XOR the byte offset with (l16&7)<<4.
#define GBM 256
#define GBN 256
#define GBK 64

__global__ void __launch_bounds__(512, 1) gemm256(const bf16_t* __restrict__ A,
                                                  const bf16_t* __restrict__ Bt,
                                                  bf16_t* __restrict__ C,
                                                  int M, int N, int K,
                                                  int nbx) {
  __shared__ __align__(16) bf16_t As[2][GBM * GBK];
  __shared__ __align__(16) bf16_t Bs[2][GBN * GBK];
  const int tid = threadIdx.x;
  const int w = tid >> 6, lane = tid & 63;
  const int quad = lane >> 4, l16 = lane & 15;
  const int wr = w >> 2, wc = w & 3;  // 2M x 4N wave grid; wave tile 128x64

  // ---- bijective XCD swizzle (grid % 8 == 0) ----
  const int wg = blockIdx.x;
  const int cpx = gridDim.x >> 3;
  const int sw = (wg & 7) * cpx + (wg >> 3);
  const int by = sw / nbx, bx = sw % nbx;
  const int m0 = by * GBM, n0 = bx * GBN;

  // ---- staging source pointers: lane (r8,g) sources granule g^r8 ----
  const int r8 = lane >> 3, g = lane & 7;
  const int gsw = (g ^ r8) * 8;  // element offset of swizzled 16B granule
  const bf16_t* gA[4];
  const bf16_t* gB[4];
#pragma unroll
  for (int j = 0; j < 4; ++j) {
    gA[j] = A + (long)(m0 + w * 32 + j * 8 + r8) * K + gsw;
    gB[j] = Bt + (long)(n0 + w * 32 + j * 8 + r8) * K + gsw;
  }

  // ---- ds_read swizzled byte offsets (per-lane constant) ----
  const int kx = (l16 & 7) << 4;
  const int ko0 = (quad * 16) ^ kx;       // k-slice 0 (k=0..31)
  const int ko1 = (64 + quad * 16) ^ kx;  // k-slice 1 (k=32..63)

  f32x4 acc[8][4] = {};  // [mt][nt]

  const int nt = K >> 6;

  // ---- prologue: stage tile 0 into buf0 ----
#pragma unroll
  for (int j = 0; j < 4; ++j) {
    GLDS(gA[j], As[0] + (w * 32 + j * 8) * GBK);
    GLDS(gB[j], Bs[0] + (w * 32 + j * 8) * GBK);
  }
  asm volatile("s_waitcnt vmcnt(0)" ::: "memory");
  __builtin_amdgcn_s_barrier();

  for (int t = 0; t < nt; ++t) {
    const bf16_t* Ab = (t & 1) ? As[1] : As[0];
    const bf16_t* Bb = (t & 1) ? Bs[1] : Bs[0];
    bf16_t* Asb = (t & 1) ? As[0] : As[1];
    bf16_t* Bsb = (t & 1) ? Bs[0] : Bs[1];
    const bool pf = (t + 1 < nt);
    const long ko = (long)(t + 1) * GBK;

    const char* Arow = (const char*)Ab + (size_t)(wr * 128 + l16) * 128;
    const char* Brow = (const char*)Bb + (size_t)(wc * 64 + l16) * 128;

    bf16x8 af[4][2], bn0[2][2], bn1[2][2];

    // ---------------- phase 0: A m-half0 + B n-half0; stage j=0,1 ----------
#pragma unroll
    for (int mt = 0; mt < 4; ++mt) {
      af[mt][0] = *(const bf16x8*)(Arow + (size_t)mt * 16 * 128 + ko0);
      af[mt][1] = *(const bf16x8*)(Arow + (size_t)mt * 16 * 128 + ko1);
    }
#pragma unroll
    for (int n = 0; n < 2; ++n) {
      bn0[n][0] = *(const bf16x8*)(Brow + (size_t)n * 16 * 128 + ko0);
      bn0[n][1] = *(const bf16x8*)(Brow + (size_t)n * 16 * 128 + ko1);
    }
    if (pf) {
      GLDS(gA[0] + ko, Asb + (w * 32) * GBK);
      GLDS(gB[0] + ko, Bsb + (w * 32) * GBK);
      GLDS(gA[1] + ko, Asb + (w * 32 + 8) * GBK);
      GLDS(gB[1] + ko, Bsb + (w * 32 + 8) * GBK);
    }
    __builtin_amdgcn_s_barrier();
    __builtin_amdgcn_s_setprio(1);
#pragma unroll
    for (int mt = 0; mt < 4; ++mt)
#pragma unroll
      for (int n = 0; n < 2; ++n) {
        acc[mt][n] = MFMA32(af[mt][0], bn0[n][0], acc[mt][n]);
        acc[mt][n] = MFMA32(af[mt][1], bn0[n][1], acc[mt][n]);
      }
    __builtin_amdgcn_s_setprio(0);
    __builtin_amdgcn_s_barrier();

    // ---------------- phase 1: B n-half1; stage j=2,3 ----------------------
#pragma unroll
    for (int n = 0; n < 2; ++n) {
      bn1[n][0] = *(const bf16x8*)(Brow + (size_t)(32 + n * 16) * 128 + ko0);
      bn1[n][1] = *(const bf16x8*)(Brow + (size_t)(32 + n * 16) * 128 + ko1);
    }
    if (pf) {
      GLDS(gA[2] + ko, Asb + (w * 32 + 16) * GBK);
      GLDS(gB[2] + ko, Bsb + (w * 32 + 16) * GBK);
      GLDS(gA[3] + ko, Asb + (w * 32 + 24) * GBK);
      GLDS(gB[3] + ko, Bsb + (w * 32 + 24) * GBK);
    }
    __builtin_amdgcn_s_barrier();
    __builtin_amdgcn_s_setprio(1);
#pragma unroll
    for (int mt = 0; mt < 4; ++mt)
#pragma unroll
      for (int n = 0; n < 2; ++n) {
        acc[mt][2 + n] = MFMA32(af[mt][0], bn1[n][0], acc[mt][2 + n]);
        acc[mt][2 + n] = MFMA32(af[mt][1], bn1[n][1], acc[mt][2 + n]);
      }
    __builtin_amdgcn_s_setprio(0);
    __builtin_amdgcn_s_barrier();

    // ---------------- phase 2: A m-half1 (overwrite af) --------------------
#pragma unroll
    for (int mt = 0; mt < 4; ++mt) {
      af[mt][0] = *(const bf16x8*)(Arow + (size_t)(64 + mt * 16) * 128 + ko0);
      af[mt][1] = *(const bf16x8*)(Arow + (size_t)(64 + mt * 16) * 128 + ko1);
    }
    __builtin_amdgcn_s_barrier();
    __builtin_amdgcn_s_setprio(1);
#pragma unroll
    for (int mt = 0; mt < 4; ++mt)
#pragma unroll
      for (int n = 0; n < 2; ++n) {
        acc[4 + mt][2 + n] = MFMA32(af[mt][0], bn1[n][0], acc[4 + mt][2 + n]);
        acc[4 + mt][2 + n] = MFMA32(af[mt][1], bn1[n][1], acc[4 + mt][2 + n]);
      }
    __builtin_amdgcn_s_setprio(0);
    __builtin_amdgcn_s_barrier();

    // ---------------- phase 3: (regs only) ---------------------------------
    __builtin_amdgcn_s_setprio(1);
#pragma unroll
    for (int mt = 0; mt < 4; ++mt)
#pragma unroll
      for (int n = 0; n < 2; ++n) {
        acc[4 + mt][n] = MFMA32(af[mt][0], bn0[n][0], acc[4 + mt][n]);
        acc[4 + mt][n] = MFMA32(af[mt][1], bn0[n][1], acc[4 + mt][n]);
      }
    __builtin_amdgcn_s_setprio(0);

    // ---- K-tile boundary: staged loads landed + all waves done reading ----
    asm volatile("s_waitcnt vmcnt(0)" ::: "memory");
    __builtin_amdgcn_s_barrier();
  }

  // ---- epilogue: C-write ----
#pragma unroll
  for (int mt = 0; mt < 8; ++mt)
#pragma unroll
    for (int n = 0; n < 4; ++n) {
      const int col = n0 + wc * 64 + n * 16 + l16;
#pragma unroll
      for (int i = 0; i < 4; ++i) {
        const int row = m0 + wr * 128 + mt * 16 + quad * 4 + i;
        C[(long)row * N + col] = (bf16_t)acc[mt][n][i];
      }
    }
}

// ---------------- GEMM (m97 structure): C[M][N] = A[M][K] @ Bt[N][K]^T -------
// ratio-2.0 economics (wave tile 64x64).  Used for the out GEMM: grid (8,32)
// = 256 blocks = exactly 1 round.
#define BM 128
#define BN 128
#define BK 32

template <typename OutT>
__global__ void __launch_bounds__(256) gemm_bt(const bf16_t* __restrict__ A,
                                               const bf16_t* __restrict__ Bt,
                                               OutT* __restrict__ C, int M,
                                               int N, int K) {
  __shared__ __align__(16) bf16_t As[BM * BK];
  __shared__ __align__(16) bf16_t Bs[BN * BK];
  const int tid = threadIdx.x;
  const int w = tid >> 6;
  const int lane = tid & 63;
  const int quad = lane >> 4, l16 = lane & 15;
  const int m0 = blockIdx.y * BM, n0 = blockIdx.x * BN;
  const int wm = (w >> 1) * 64, wn = (w & 1) * 64;
  const int srow = tid >> 2;       // 0..63
  const int scol = (tid & 3) * 8;  // 0,8,16,24

  const bf16_t* Ag0 = A + (long)(m0 + srow) * K + scol;
  const bf16_t* Ag1 = Ag0 + (long)64 * K;
  const bf16_t* Bg0 = Bt + (long)(n0 + srow) * K + scol;
  const bf16_t* Bg1 = Bg0 + (long)64 * K;
  bf16_t* lA0 = As + tid * 8;  // == srow*32 + scol
  bf16_t* lA1 = As + 2048 + tid * 8;
  bf16_t* lB0 = Bs + tid * 8;
  bf16_t* lB1 = Bs + 2048 + tid * 8;

  f32x4 acc[4][4] = {};

  for (int k0 = 0; k0 < K; k0 += BK) {
    GLDS(Ag0 + k0, lA0);
    GLDS(Ag1 + k0, lA1);
    GLDS(Bg0 + k0, lB0);
    GLDS(Bg1 + k0, lB1);
    __syncthreads();
    bf16x8 af[4], bfr[4];
#pragma unroll
    for (int t = 0; t < 4; ++t) {
      af[t] = *(const bf16x8*)(As + (wm + t * 16 + l16) * BK + quad * 8);
      bfr[t] = *(const bf16x8*)(Bs + (wn + t * 16 + l16) * BK + quad * 8);
    }
#pragma unroll
    for (int mt = 0; mt < 4; ++mt)
#pragma unroll
      for (int nt = 0; nt < 4; ++nt)
        acc[mt][nt] = MFMA32(af[mt], bfr[nt], acc[mt][nt]);
    __syncthreads();
  }

#pragma unroll
  for (int mt = 0; mt < 4; ++mt)
#pragma unroll
    for (int nt = 0; nt < 4; ++nt) {
      const int col = n0 + wn + nt * 16 + l16;
#pragma unroll
      for (int i = 0; i < 4; ++i) {
        const int row = m0 + wm + mt * 16 + quad * 4 + i;
        C[(long)row * N + col] = (OutT)acc[mt][nt][i];
      }
    }
}

// ---------------- transpose v slice of proj -> vt[(b,h)][d][t] (plain, R3) ---
__global__ void __launch_bounds__(256) transpose_v(const bf16_t* __restrict__ proj,
                                                   bf16_t* __restrict__ vt) {
  __shared__ bf16_t tile[32][34];
  const int bh = blockIdx.z;
  const int b = bh >> 4, h = bh & 15;
  const int t0 = blockIdx.x * 32, d0 = blockIdx.y * 32;
  const int tx = threadIdx.x & 31, ty = threadIdx.x >> 5;
  const bf16_t* src = proj + (long)(b * T_SEQ) * NPROJ + 4096 + h * 128;
#pragma unroll
  for (int i = 0; i < 32; i += 8)
    tile[ty + i][tx] = src[(long)(t0 + ty + i) * NPROJ + d0 + tx];
  __syncthreads();
  bf16_t* dst = vt + ((long)bh * DV) * T_SEQ;
#pragma unroll
  for (int i = 0; i < 32; i += 8)
    dst[(long)(d0 + ty + i) * T_SEQ + t0 + tx] = tile[tx][ty + i];
}

// ---------------- attention: split-stream, one (qblk, stream) per block ------
// EXACT R3 kernel (74.7-76.3us measured).  grid: (2048). x>>7 = qi (qblk =
// 15-qi, big first / LPT), st = (x>>6)&1, bh = x&63 (x%8 tracks bh ->
// same-(b,h) blocks share an XCD's L2).  4 waves; wave w owns 16 q rows.
__global__ void __launch_bounds__(256) attn_kernel(const bf16_t* __restrict__ proj,
                                                   const bf16_t* __restrict__ vt,
                                                   _Float16* __restrict__ a1,
                                                   _Float16* __restrict__ a2) {
  const int x = blockIdx.x;
  const int qblk = 15 - (x >> 7);
  const int st = (x >> 6) & 1;
  const int bh = x & 63;
  const int b = bh >> 4, h = bh & 15;
  const int tid = threadIdx.x;
  const int w = tid >> 6, lane = tid & 63;
  const int quad = lane >> 4, l16 = lane & 15;
  const long bT = (long)b * T_SEQ;

  __shared__ __align__(16) bf16_t Ks[64 * KSTR];  // [key][dim]
  __shared__ __align__(16) bf16_t Vs[DV * KSTR];  // [dim][key]

  // ---- staging source pointers (this stream's K; shared V) ----
  const int koff = h * 64 + 2048 + st * 1024;
  const bf16_t* gK = proj + (bT + (tid >> 2)) * (long)NPROJ + koff + (tid & 3) * 16;
  const bf16_t* gV = vt + (long)bh * DV * T_SEQ + (long)(tid >> 1) * T_SEQ +
                     (tid & 1) * 32;
  const int kwK = (tid >> 2) * KSTR + (tid & 3) * 16;
  const int kwV = (tid >> 1) * KSTR + (tid & 1) * 32;

  const float sc = 0.125f * LOG2E;  // 1/sqrt(64) folded with log2(e)
  const int q0 = qblk * 64 + w * 16;
  const int qg = q0 + l16;  // this lane's q row (all fragments)

  // ---- Q fragments (B-operand role), this stream only ----
  const bf16_t* qrow = proj + (bT + qg) * (long)NPROJ + h * 64 + st * 1024;
  bf16x8 aq[2];
  aq[0] = *(const bf16x8*)(qrow + quad * 8);
  aq[1] = *(const bf16x8*)(qrow + 32 + quad * 8);

  f32x4 O[8] = {};  // O^T[d=f*16+quad*4+reg][q=l16]
  float m = -3.0e38f, l = 0.f;
  const bf16x4 one4 = {(bf16_t)1.0f, (bf16_t)1.0f, (bf16_t)1.0f, (bf16_t)1.0f};

  const int kend_blk = qblk * 64 + 64;
  const int kend_w = q0 + 16;

  // ---- prime the register pipeline with tile kt=0 ----
  bf16x8 rK[2], rV[4];
  rK[0] = *(const bf16x8*)(gK);
  rK[1] = *(const bf16x8*)(gK + 8);
#pragma unroll
  for (int j = 0; j < 4; ++j) rV[j] = *(const bf16x8*)(gV + j * 8);

  for (int kt = 0; kt < kend_blk; kt += 64) {
    // ---- commit staged registers to LDS ----
    *(bf16x8*)(Ks + kwK) = rK[0];
    *(bf16x8*)(Ks + kwK + 8) = rK[1];
#pragma unroll
    for (int j = 0; j < 4; ++j) *(bf16x8*)(Vs + kwV + j * 8) = rV[j];
    __syncthreads();

    // ---- prefetch next tile into registers (overlaps compute) ----
    if (kt + 64 < kend_blk) {
      const long ko = (long)(kt + 64) * NPROJ;
      rK[0] = *(const bf16x8*)(gK + ko);
      rK[1] = *(const bf16x8*)(gK + ko + 8);
#pragma unroll
      for (int j = 0; j < 4; ++j)
        rV[j] = *(const bf16x8*)(gV + kt + 64 + j * 8);
    }

    if (kt < kend_w) {
      // ---- S^T = K Q^T : A=K-frag (from LDS), B=Q-frag (regs) ----
      f32x4 s[4];
#pragma unroll
      for (int c = 0; c < 4; ++c) {
        const bf16_t* kr = Ks + (c * 16 + l16) * KSTR;
        bf16x8 ka0 = *(const bf16x8*)(kr + quad * 8);
        bf16x8 ka1 = *(const bf16x8*)(kr + 32 + quad * 8);
        f32x4 z = {};
        z = MFMA32(ka0, aq[0], z);
        z = MFMA32(ka1, aq[1], z);
        s[c] = z;
      }
      // ---- causal mask (diagonal tile only) + in-lane TREE max ----
      if (kt + 63 > q0) {
#pragma unroll
        for (int c = 0; c < 4; ++c)
#pragma unroll
          for (int i = 0; i < 4; ++i) {
            const int key = kt + c * 16 + quad * 4 + i;
            if (key > qg) s[c][i] = -1e30f;
          }
      }
      float t[4];
#pragma unroll
      for (int c = 0; c < 4; ++c)
        t[c] = fmaxf(fmaxf(s[c][0], s[c][1]), fmaxf(s[c][2], s[c][3]));
      float mx = fmaxf(fmaxf(t[0], t[1]), fmaxf(t[2], t[3]));
      mx = fmaxf(mx, __shfl_xor(mx, 16));
      mx = fmaxf(mx, __shfl_xor(mx, 32));
      // ---- defer-rescale (T13) ----
      if (!__all(mx <= m + RTHR)) {
        const float mn = fmaxf(m, mx);
        const float al = exp2f((m - mn) * sc);
        m = mn;
#pragma unroll
        for (int f = 0; f < 8; ++f)
#pragma unroll
          for (int i = 0; i < 4; ++i) O[f][i] *= al;
        l *= al;
      }
      // ---- P = exp2(fma(s,sc,-m*sc)), packed bf16x4 per c ----
      const float ms = m * sc;
      bf16x4 pc[4];
#pragma unroll
      for (int c = 0; c < 4; ++c)
#pragma unroll
        for (int i = 0; i < 4; ++i)
          pc[c][i] = (bf16_t)exp2f(fmaf(s[c][i], sc, -ms));
      // ---- row-sum l via ones-row MFMA ----
      f32x4 la = {};
#pragma unroll
      for (int c = 0; c < 4; ++c) la = MFMA16(one4, pc[c], la);
      // ---- PV: O^T += V^T P^T ----
#pragma unroll
      for (int c = 0; c < 4; ++c) {
#pragma unroll
        for (int f = 0; f < 8; ++f) {
          bf16x4 va =
              *(const bf16x4*)(Vs + (f * 16 + l16) * KSTR + c * 16 + quad * 4);
          O[f] = MFMA16(va, pc[c], O[f]);
        }
      }
      l += la[0];
    }
    __syncthreads();
  }

  // ---- normalize and store per-stream a_s = (P/l)V as fp16 ----
  const float inv = 1.0f / l;
  _Float16* ob = st ? a2 : a1;
  _Float16* dst = ob + ((bT + qg) * 16 + h) * (long)128 + quad * 4;
#pragma unroll
  for (int f = 0; f < 8; ++f) {
    f16x4 o = {(_Float16)(O[f][0] * inv), (_Float16)(O[f][1] * inv),
               (_Float16)(O[f][2] * inv), (_Float16)(O[f][3] * inv)};
    *(f16x4*)(dst + f * 16) = o;
  }
}

// ---------------- combine (lambda fused): y = a1 - lam*a2, subLN, -> bf16 ----
// One wave per (token,head) unit; lane holds 2 dims.  Wave computes its own
// head's lambda via a lane-wise dot + the same shfl-reduce tree it already
// runs for subLN (lq/lk are 16KB total -> L2-resident).  IN PLACE over a1.
__global__ void __launch_bounds__(256) combine_kernel(
    const _Float16* __restrict__ a1, const _Float16* __restrict__ a2,
    const float* __restrict__ lq1, const float* __restrict__ lk1,
    const float* __restrict__ lq2, const float* __restrict__ lk2,
    bf16_t* __restrict__ yln) {
  const int unit = blockIdx.x * 4 + (threadIdx.x >> 6);  // 0..65535 = r*16+h
  const int lane = threadIdx.x & 63;
  const int h = unit & 15;
  // ---- lambda for this head (per-wave) ----
  float p1 = lq1[h * 64 + lane] * lk1[h * 64 + lane];
  float p2 = lq2[h * 64 + lane] * lk2[h * 64 + lane];
#pragma unroll
  for (int off = 1; off < 64; off <<= 1) {
    p1 += __shfl_xor(p1, off);
    p2 += __shfl_xor(p2, off);
  }
  const float lam = expf(p1) - expf(p2) + LAMBDA_INIT;

  const long base = (long)unit * 128 + lane * 2;
  f16x2 v1 = *(const f16x2*)(a1 + base);
  f16x2 v2 = *(const f16x2*)(a2 + base);
  float y0 = (float)v1[0] - lam * (float)v2[0];
  float y1 = (float)v1[1] - lam * (float)v2[1];
  float sm = y0 + y1, sq = y0 * y0 + y1 * y1;
#pragma unroll
  for (int off = 1; off < 64; off <<= 1) {
    sm += __shfl_xor(sm, off);
    sq += __shfl_xor(sq, off);
  }
  const float mu = sm * (1.0f / 128.0f);
  const float var = sq * (1.0f / 128.0f) - mu * mu;
  const float rs = rsqrtf(var + 1e-5f) * ONE_MINUS_LI;
  bf16x2 o = {(bf16_t)((y0 - mu) * rs), (bf16_t)((y1 - mu) * rs)};
  *(bf16x2*)(yln + base) = o;
}

// ---------------------------------------------------------------------------
extern "C" void kernel_launch(void* const* d_in, const int* in_sizes, int n_in,
                              void* d_out, int out_size, void* d_ws,
                              size_t ws_size, hipStream_t stream) {
  const float* x = (const float*)d_in[0];
  const float* Wq1 = (const float*)d_in[1];
  const float* Wq2 = (const float*)d_in[2];
  const float* Wk1 = (const float*)d_in[3];
  const float* Wk2 = (const float*)d_in[4];
  const float* Wv = (const float*)d_in[5];
  const float* Wc = (const float*)d_in[6];
  const float* lq1 = (const float*)d_in[7];
  const float* lk1 = (const float*)d_in[8];
  const float* lq2 = (const float*)d_in[9];
  const float* lk2 = (const float*)d_in[10];
  float* out = (float*)d_out;

  char* ws = (char*)d_ws;
  bf16_t* wcat = (bf16_t*)(ws + OFF_WCAT);
  bf16_t* xb = (bf16_t*)(ws + OFF_XB);
  bf16_t* wct = (bf16_t*)(ws + OFF_WCT);
  bf16_t* projb = (bf16_t*)(ws + OFF_PROJ);
  bf16_t* vtb = (bf16_t*)(ws + OFF_VT);
  bf16_t* ylnb = (bf16_t*)(ws + OFF_YLN);
  _Float16* a1b = (_Float16*)(ws + OFF_YLN);   // aliases yln (in-place combine)
  _Float16* a2b = (_Float16*)(ws + OFF_WCAT);  // aliases wcat+xb (dead after proj)

  // fused prep: cast_x + all 4 weight transpose-casts (1 launch, was 5)
  prep_kernel<<<dim3(12288), 256, 0, stream>>>(x, Wq1, Wq2, Wk1, Wk2, Wv, Wc,
                                               xb, wcat, wct);
  // proj = xb @ wcat^T : M=4096 N=6144 K=1024 ; 16x24 = 384 tiles (384%8==0)
  gemm256<<<dim3(384), 512, 0, stream>>>(xb, wcat, projb, 4096, 6144, 1024, 24);
  transpose_v<<<dim3(32, 4, 64), 256, 0, stream>>>(projb, vtb);
  attn_kernel<<<dim3(2048), 256, 0, stream>>>(projb, vtb, a1b, a2b);
  combine_kernel<<<dim3(16384), 256, 0, stream>>>(a1b, a2b, lq1, lk1, lq2, lk2,
                                                  ylnb);
  // out = yln @ wc^T : M=4096 N=1024 K=2048  (BN=128 -> 256 blocks, 1 round)
  gemm_bt<float><<<dim3(8, 32), 256, 0, stream>>>(ylnb, wct, out, 4096, 1024, 2048);
}

// Round 12
// 303.123 us; speedup vs baseline: 1.0477x; 1.0477x over previous
//
#include <hip/hip_runtime.h>

// ---------------------------------------------------------------------------
// DiffAttention forward, bf16 MFMA pipeline.  B=4 T=1024 C=1024 H=16 hs=64 dv=128.
// CONSOLIDATION ROUND: exact R4 configuration — the best MEASURED total
// (305.9us).  R20 (R11 post-mortem): launch-fusion (10->6) did NOT help
// (313.9->317.6); the ~100us wall-vs-kernel-sum gap is constant regardless
// of launch count => fixed harness/graph overhead, not recoverable.  The
// prep/combine fusion bundle itself was ~+9us (prep's runtime-indexed Ws[4]
// = rule-#20 scratch; combine extra work).  All fusions reverted.
//   1. cast x -> bf16; transpose-cast weights -> W^T[n][k] bf16 (5 launches)
//   2. proj GEMM: R4 gemm256 (256x256, BK=64, 8 waves, 4-phase, T2 swizzle,
//      vmcnt(0) boundary) — best measured proj (~72us; ring/2-phase/chunked
//      alternatives all slower: R5/R6/R9).
//   3. transpose v slice -> vt[(b,h)][dim][token] (plain)
//   4. attention: split-stream, one (qblk, stream) per 256-thr block, LPT
//      grid 2048 — best measured attn (74.7us).  Paired/permuted (R8) and
//      no-LDS (R2) variants both regressed.
//   4b. combine: y = a1 - lam_h*a2, subLN(128), *(1-LI), bf16 -> yln.
//   5. out GEMM: gemm_bt_n64 (BN=64, 512 blocks; BN=128 measured neutral).
// MFMA mappings (HW-verified): A[m=lane&15][k=quad*8+j] (K=32) / quad*4+j
// (K=16); B^T[n=lane&15][k=same]; C/D: col=lane&15, row=quad*4+reg.
// Ledger: R8 host-guard; R10/R2 keep LDS staging; R13 grid-round tails;
// R14 wave-tile LDS economics >= 2.5; R16 infra-fail => resubmit identical;
// R17 attn conflicts not critical path; R18 proj frozen at 4-phase;
// R20 fusion reverted, fixed overhead identified.
// ---------------------------------------------------------------------------

#define T_SEQ 1024
#define NH 16
#define DV 128
#define NPROJ 6144
#define KSTR 72  // attn K/V LDS row stride (elements)

typedef __bf16 bf16_t;
typedef __bf16 bf16x8 __attribute__((ext_vector_type(8)));
typedef __bf16 bf16x4 __attribute__((ext_vector_type(4)));
typedef __bf16 bf16x2 __attribute__((ext_vector_type(2)));
typedef _Float16 f16x4 __attribute__((ext_vector_type(4)));
typedef _Float16 f16x2 __attribute__((ext_vector_type(2)));
typedef short s16x4 __attribute__((ext_vector_type(4)));
typedef float f32x4 __attribute__((ext_vector_type(4)));

#define LAMBDA_INIT 0.35550906759096928f
#define ONE_MINUS_LI 0.6444909324090307f
#define LOG2E 1.4426950408889634f
// defer-rescale threshold in RAW score units: 8 / (0.125*log2e) ~= 44.36
#define RTHR 44.36f

#if __has_builtin(__builtin_amdgcn_mfma_f32_16x16x16_bf16)
#define MFMA16(a, b, c) __builtin_amdgcn_mfma_f32_16x16x16_bf16(a, b, c, 0, 0, 0)
#elif __has_builtin(__builtin_amdgcn_mfma_f32_16x16x16bf16_1k)
#define MFMA16(a, b, c)                                                       \
  __builtin_amdgcn_mfma_f32_16x16x16bf16_1k(                                  \
      __builtin_bit_cast(s16x4, a), __builtin_bit_cast(s16x4, b), c, 0, 0, 0)
#else
#define MFMA16(a, b, c) (c)  // host pass only — never executed
#endif

#define MFMA32(a, b, c) __builtin_amdgcn_mfma_f32_16x16x32_bf16(a, b, c, 0, 0, 0)

// async global->LDS, 16B/lane.
#define GLDS(g, l)                                                            \
  __builtin_amdgcn_global_load_lds(                                           \
      (const __attribute__((address_space(1))) void*)(g),                     \
      (__attribute__((address_space(3))) void*)(l), 16, 0, 0)

// ---------------- workspace layout (bytes) ----------------
static const size_t OFF_WCAT = 0;                                  // 6144x1024 bf16
static const size_t OFF_XB = OFF_WCAT + (size_t)6144 * 1024 * 2;   // 4096x1024 bf16
static const size_t OFF_WCT = OFF_XB + (size_t)4096 * 1024 * 2;    // 1024x2048 bf16
static const size_t OFF_PROJ = OFF_WCT + (size_t)2048 * 1024 * 2;  // 4096x6144 bf16
static const size_t OFF_VT = OFF_PROJ + (size_t)4096 * 6144 * 2;   // 64*128*1024 bf16
static const size_t OFF_YLN = OFF_VT + (size_t)64 * 128 * 1024 * 2;// 4096x2048 bf16
static const size_t OFF_LAM = OFF_YLN + (size_t)4096 * 2048 * 2;   // 16 f32
// a1 (fp16, 16.78 MB) aliases YLN (combine rewrites in place); a2 aliases
// WCAT+XB (dead after proj GEMM).

// ---------------- elementwise cast x -> bf16 ----------------
__global__ void __launch_bounds__(256) cast_x(const float* __restrict__ x,
                                              bf16_t* __restrict__ o) {
  const int i = (blockIdx.x * 256 + threadIdx.x) * 4;
  float4 v = *(const float4*)(x + i);
  bf16x4 r = {(bf16_t)v.x, (bf16_t)v.y, (bf16_t)v.z, (bf16_t)v.w};
  *(bf16x4*)(o + i) = r;
}

// ---------------- transpose-cast weight W[K][N] fp32 -> Wt[row0+n][k] bf16 ----
__device__ __forceinline__ void tcast_body(const float* __restrict__ W,
                                           bf16_t* __restrict__ Wt, int K,
                                           int N, int row0) {
  __shared__ float tile[32][33];
  const int k0 = blockIdx.x * 32, n0 = blockIdx.y * 32;
  const int tx = threadIdx.x & 31, ty = threadIdx.x >> 5;  // 32x8
#pragma unroll
  for (int i = 0; i < 32; i += 8)
    tile[ty + i][tx] = W[(long)(k0 + ty + i) * N + n0 + tx];
  __syncthreads();
#pragma unroll
  for (int i = 0; i < 32; i += 8)
    Wt[(long)(row0 + n0 + ty + i) * K + k0 + tx] = (bf16_t)tile[tx][ty + i];
}

__global__ void __launch_bounds__(256) tcast_w(const float* __restrict__ W,
                                               bf16_t* __restrict__ Wt, int K,
                                               int N, int row0) {
  tcast_body(W, Wt, K, N, row0);
}

// fused: the four 1024x1024 q/k weights in one launch (z selects)
__global__ void __launch_bounds__(256) tcast_w4(const float* __restrict__ W0,
                                                const float* __restrict__ W1,
                                                const float* __restrict__ W2,
                                                const float* __restrict__ W3,
                                                bf16_t* __restrict__ Wt) {
  const float* Ws[4] = {W0, W1, W2, W3};
  tcast_body(Ws[blockIdx.z], Wt, 1024, 1024, blockIdx.z * 1024);
}

// ---------------- per-head lambda ----------------
__global__ void lam_kernel(const float* __restrict__ lq1,
                           const float* __restrict__ lk1,
                           const float* __restrict__ lq2,
                           const float* __restrict__ lk2,
                           float* __restrict__ lam) {
  const int h = threadIdx.x;
  if (h < NH) {
    float d1 = 0.f, d2 = 0.f;
    for (int i = 0; i < 64; ++i) {
      d1 += lq1[h * 64 + i] * lk1[h * 64 + i];
      d2 += lq2[h * 64 + i] * lk2[h * 64 + i];
    }
    lam[h] = expf(d1) - expf(d2) + LAMBDA_INIT;
  }
}

// ---------------- proj GEMM: R4 256x256 4-phase (measured-best, FROZEN) -----
// C[M][N] bf16 = A[M][K] @ Bt[N][K]^T.  grid.x = (M/256)*(N/256), %8 == 0.
// LDS: 2 K-tile buffers (A 256x64 + B 256x64 each) = 128 KiB.  Staging for
// tile t+1 goes into buf^1, issued in phases 0-1, drained by ONE vmcnt(0)+
// barrier at the tile boundary.  T2 swizzle: LDS granule g of row r holds
// global granule g^(r&7); reads XOR the byte offset with (l16&7)<<4.
#define GBM 256
#define GBN 256
#define GBK 64

__global__ void __launch_bounds__(512, 1) gemm256(const bf16_t* __restrict__ A,
                                                  const bf16_t* __restrict__ Bt,
                                                  bf16_t* __restrict__ C,
                                                  int M, int N, int K,
                                                  int nbx) {
  __shared__ __align__(16) bf16_t As[2][GBM * GBK];
  __shared__ __align__(16) bf16_t Bs[2][GBN * GBK];
  const int tid = threadIdx.x;
  const int w = tid >> 6, lane = tid & 63;
  const int quad = lane >> 4, l16 = lane & 15;
  const int wr = w >> 2, wc = w & 3;  // 2M x 4N wave grid; wave tile 128x64

  // ---- bijective XCD swizzle (grid % 8 == 0) ----
  const int wg = blockIdx.x;
  const int cpx = gridDim.x >> 3;
  const int sw = (wg & 7) * cpx + (wg >> 3);
  const int by = sw / nbx, bx = sw % nbx;
  const int m0 = by * GBM, n0 = bx * GBN;

  // ---- staging source pointers: lane (r8,g) sources granule g^r8 ----
  const int r8 = lane >> 3, g = lane & 7;
  const int gsw = (g ^ r8) * 8;  // element offset of swizzled 16B granule
  const bf16_t* gA[4];
  const bf16_t* gB[4];
#pragma unroll
  for (int j = 0; j < 4; ++j) {
    gA[j] = A + (long)(m0 + w * 32 + j * 8 + r8) * K + gsw;
    gB[j] = Bt + (long)(n0 + w * 32 + j * 8 + r8) * K + gsw;
  }

  // ---- ds_read swizzled byte offsets (per-lane constant) ----
  const int kx = (l16 & 7) << 4;
  const int ko0 = (quad * 16) ^ kx;       // k-slice 0 (k=0..31)
  const int ko1 = (64 + quad * 16) ^ kx;  // k-slice 1 (k=32..63)

  f32x4 acc[8][4] = {};  // [mt][nt]

  const int nt = K >> 6;

  // ---- prologue: stage tile 0 into buf0 ----
#pragma unroll
  for (int j = 0; j < 4; ++j) {
    GLDS(gA[j], As[0] + (w * 32 + j * 8) * GBK);
    GLDS(gB[j], Bs[0] + (w * 32 + j * 8) * GBK);
  }
  asm volatile("s_waitcnt vmcnt(0)" ::: "memory");
  __builtin_amdgcn_s_barrier();

  for (int t = 0; t < nt; ++t) {
    const bf16_t* Ab = (t & 1) ? As[1] : As[0];
    const bf16_t* Bb = (t & 1) ? Bs[1] : Bs[0];
    bf16_t* Asb = (t & 1) ? As[0] : As[1];
    bf16_t* Bsb = (t & 1) ? Bs[0] : Bs[1];
    const bool pf = (t + 1 < nt);
    const long ko = (long)(t + 1) * GBK;

    const char* Arow = (const char*)Ab + (size_t)(wr * 128 + l16) * 128;
    const char* Brow = (const char*)Bb + (size_t)(wc * 64 + l16) * 128;

    bf16x8 af[4][2], bn0[2][2], bn1[2][2];

    // ---------------- phase 0: A m-half0 + B n-half0; stage j=0,1 ----------
#pragma unroll
    for (int mt = 0; mt < 4; ++mt) {
      af[mt][0] = *(const bf16x8*)(Arow + (size_t)mt * 16 * 128 + ko0);
      af[mt][1] = *(const bf16x8*)(Arow + (size_t)mt * 16 * 128 + ko1);
    }
#pragma unroll
    for (int n = 0; n < 2; ++n) {
      bn0[n][0] = *(const bf16x8*)(Brow + (size_t)n * 16 * 128 + ko0);
      bn0[n][1] = *(const bf16x8*)(Brow + (size_t)n * 16 * 128 + ko1);
    }
    if (pf) {
      GLDS(gA[0] + ko, Asb + (w * 32) * GBK);
      GLDS(gB[0] + ko, Bsb + (w * 32) * GBK);
      GLDS(gA[1] + ko, Asb + (w * 32 + 8) * GBK);
      GLDS(gB[1] + ko, Bsb + (w * 32 + 8) * GBK);
    }
    __builtin_amdgcn_s_barrier();
    __builtin_amdgcn_s_setprio(1);
#pragma unroll
    for (int mt = 0; mt < 4; ++mt)
#pragma unroll
      for (int n = 0; n < 2; ++n) {
        acc[mt][n] = MFMA32(af[mt][0], bn0[n][0], acc[mt][n]);
        acc[mt][n] = MFMA32(af[mt][1], bn0[n][1], acc[mt][n]);
      }
    __builtin_amdgcn_s_setprio(0);
    __builtin_amdgcn_s_barrier();

    // ---------------- phase 1: B n-half1; stage j=2,3 ----------------------
#pragma unroll
    for (int n = 0; n < 2; ++n) {
      bn1[n][0] = *(const bf16x8*)(Brow + (size_t)(32 + n * 16) * 128 + ko0);
      bn1[n][1] = *(const bf16x8*)(Brow + (size_t)(32 + n * 16) * 128 + ko1);
    }
    if (pf) {
      GLDS(gA[2] + ko, Asb + (w * 32 + 16) * GBK);
      GLDS(gB[2] + ko, Bsb + (w * 32 + 16) * GBK);
      GLDS(gA[3] + ko, Asb + (w * 32 + 24) * GBK);
      GLDS(gB[3] + ko, Bsb + (w * 32 + 24) * GBK);
    }
    __builtin_amdgcn_s_barrier();
    __builtin_amdgcn_s_setprio(1);
#pragma unroll
    for (int mt = 0; mt < 4; ++mt)
#pragma unroll
      for (int n = 0; n < 2; ++n) {
        acc[mt][2 + n] = MFMA32(af[mt][0], bn1[n][0], acc[mt][2 + n]);
        acc[mt][2 + n] = MFMA32(af[mt][1], bn1[n][1], acc[mt][2 + n]);
      }
    __builtin_amdgcn_s_setprio(0);
    __builtin_amdgcn_s_barrier();

    // ---------------- phase 2: A m-half1 (overwrite af) --------------------
#pragma unroll
    for (int mt = 0; mt < 4; ++mt) {
      af[mt][0] = *(const bf16x8*)(Arow + (size_t)(64 + mt * 16) * 128 + ko0);
      af[mt][1] = *(const bf16x8*)(Arow + (size_t)(64 + mt * 16) * 128 + ko1);
    }
    __builtin_amdgcn_s_barrier();
    __builtin_amdgcn_s_setprio(1);
#pragma unroll
    for (int mt = 0; mt < 4; ++mt)
#pragma unroll
      for (int n = 0; n < 2; ++n) {
        acc[4 + mt][2 + n] = MFMA32(af[mt][0], bn1[n][0], acc[4 + mt][2 + n]);
        acc[4 + mt][2 + n] = MFMA32(af[mt][1], bn1[n][1], acc[4 + mt][2 + n]);
      }
    __builtin_amdgcn_s_setprio(0);
    __builtin_amdgcn_s_barrier();

    // ---------------- phase 3: (regs only) ---------------------------------
    __builtin_amdgcn_s_setprio(1);
#pragma unroll
    for (int mt = 0; mt < 4; ++mt)
#pragma unroll
      for (int n = 0; n < 2; ++n) {
        acc[4 + mt][n] = MFMA32(af[mt][0], bn0[n][0], acc[4 + mt][n]);
        acc[4 + mt][n] = MFMA32(af[mt][1], bn0[n][1], acc[4 + mt][n]);
      }
    __builtin_amdgcn_s_setprio(0);

    // ---- K-tile boundary: staged loads landed + all waves done reading ----
    asm volatile("s_waitcnt vmcnt(0)" ::: "memory");
    __builtin_amdgcn_s_barrier();
  }

  // ---- epilogue: C-write ----
#pragma unroll
  for (int mt = 0; mt < 8; ++mt)
#pragma unroll
    for (int n = 0; n < 4; ++n) {
      const int col = n0 + wc * 64 + n * 16 + l16;
#pragma unroll
      for (int i = 0; i < 4; ++i) {
        const int row = m0 + wr * 128 + mt * 16 + quad * 4 + i;
        C[(long)row * N + col] = (bf16_t)acc[mt][n][i];
      }
    }
}

// ---------------- GEMM, BN=64 variant (out: M=4096 N=1024 -> 512 blocks) ----
#define BM 128
#define BK 32

template <typename OutT>
__global__ void __launch_bounds__(256) gemm_bt_n64(const bf16_t* __restrict__ A,
                                                   const bf16_t* __restrict__ Bt,
                                                   OutT* __restrict__ C, int M,
                                                   int N, int K) {
  __shared__ __align__(16) bf16_t As[BM * BK];
  __shared__ __align__(16) bf16_t Bs[64 * BK];
  const int tid = threadIdx.x;
  const int w = tid >> 6;
  const int lane = tid & 63;
  const int quad = lane >> 4, l16 = lane & 15;
  const int m0 = blockIdx.y * BM, n0 = blockIdx.x * 64;
  const int wm = (w >> 1) * 64, wn = (w & 1) * 32;
  const int srow = tid >> 2;       // 0..63
  const int scol = (tid & 3) * 8;  // 0,8,16,24

  const bf16_t* Ag0 = A + (long)(m0 + srow) * K + scol;
  const bf16_t* Ag1 = Ag0 + (long)64 * K;
  const bf16_t* Bg0 = Bt + (long)(n0 + srow) * K + scol;
  bf16_t* lA0 = As + tid * 8;
  bf16_t* lA1 = As + 2048 + tid * 8;
  bf16_t* lB0 = Bs + tid * 8;

  f32x4 acc[4][2] = {};

  for (int k0 = 0; k0 < K; k0 += BK) {
    GLDS(Ag0 + k0, lA0);
    GLDS(Ag1 + k0, lA1);
    GLDS(Bg0 + k0, lB0);
    __syncthreads();
    bf16x8 af[4], bfr[2];
#pragma unroll
    for (int t = 0; t < 4; ++t)
      af[t] = *(const bf16x8*)(As + (wm + t * 16 + l16) * BK + quad * 8);
#pragma unroll
    for (int t = 0; t < 2; ++t)
      bfr[t] = *(const bf16x8*)(Bs + (wn + t * 16 + l16) * BK + quad * 8);
#pragma unroll
    for (int mt = 0; mt < 4; ++mt)
#pragma unroll
      for (int ntt = 0; ntt < 2; ++ntt)
        acc[mt][ntt] = MFMA32(af[mt], bfr[ntt], acc[mt][ntt]);
    __syncthreads();
  }

#pragma unroll
  for (int mt = 0; mt < 4; ++mt)
#pragma unroll
    for (int ntt = 0; ntt < 2; ++ntt) {
      const int col = n0 + wn + ntt * 16 + l16;
#pragma unroll
      for (int i = 0; i < 4; ++i) {
        const int row = m0 + wm + mt * 16 + quad * 4 + i;
        C[(long)row * N + col] = (OutT)acc[mt][ntt][i];
      }
    }
}

// ---------------- transpose v slice of proj -> vt[(b,h)][d][t] (plain) -------
__global__ void __launch_bounds__(256) transpose_v(const bf16_t* __restrict__ proj,
                                                   bf16_t* __restrict__ vt) {
  __shared__ bf16_t tile[32][34];
  const int bh = blockIdx.z;
  const int b = bh >> 4, h = bh & 15;
  const int t0 = blockIdx.x * 32, d0 = blockIdx.y * 32;
  const int tx = threadIdx.x & 31, ty = threadIdx.x >> 5;
  const bf16_t* src = proj + (long)(b * T_SEQ) * NPROJ + 4096 + h * 128;
#pragma unroll
  for (int i = 0; i < 32; i += 8)
    tile[ty + i][tx] = src[(long)(t0 + ty + i) * NPROJ + d0 + tx];
  __syncthreads();
  bf16_t* dst = vt + ((long)bh * DV) * T_SEQ;
#pragma unroll
  for (int i = 0; i < 32; i += 8)
    dst[(long)(d0 + ty + i) * T_SEQ + t0 + tx] = tile[tx][ty + i];
}

// ---------------- attention: split-stream, one (qblk, stream) per block ------
// Best measured attn (74.7us, R4 profile).  grid: (2048). x>>7 = qi (qblk =
// 15-qi, big first / LPT), st = (x>>6)&1, bh = x&63 (x%8 tracks bh ->
// same-(b,h) blocks share an XCD's L2).  4 waves; wave w owns 16 q rows.
__global__ void __launch_bounds__(256) attn_kernel(const bf16_t* __restrict__ proj,
                                                   const bf16_t* __restrict__ vt,
                                                   _Float16* __restrict__ a1,
                                                   _Float16* __restrict__ a2) {
  const int x = blockIdx.x;
  const int qblk = 15 - (x >> 7);
  const int st = (x >> 6) & 1;
  const int bh = x & 63;
  const int b = bh >> 4, h = bh & 15;
  const int tid = threadIdx.x;
  const int w = tid >> 6, lane = tid & 63;
  const int quad = lane >> 4, l16 = lane & 15;
  const long bT = (long)b * T_SEQ;

  __shared__ __align__(16) bf16_t Ks[64 * KSTR];  // [key][dim]
  __shared__ __align__(16) bf16_t Vs[DV * KSTR];  // [dim][key]

  // ---- staging source pointers (this stream's K; shared V) ----
  const int koff = h * 64 + 2048 + st * 1024;
  const bf16_t* gK = proj + (bT + (tid >> 2)) * (long)NPROJ + koff + (tid & 3) * 16;
  const bf16_t* gV = vt + (long)bh * DV * T_SEQ + (long)(tid >> 1) * T_SEQ +
                     (tid & 1) * 32;
  const int kwK = (tid >> 2) * KSTR + (tid & 3) * 16;
  const int kwV = (tid >> 1) * KSTR + (tid & 1) * 32;

  const float sc = 0.125f * LOG2E;  // 1/sqrt(64) folded with log2(e)
  const int q0 = qblk * 64 + w * 16;
  const int qg = q0 + l16;  // this lane's q row (all fragments)

  // ---- Q fragments (B-operand role), this stream only ----
  const bf16_t* qrow = proj + (bT + qg) * (long)NPROJ + h * 64 + st * 1024;
  bf16x8 aq[2];
  aq[0] = *(const bf16x8*)(qrow + quad * 8);
  aq[1] = *(const bf16x8*)(qrow + 32 + quad * 8);

  f32x4 O[8] = {};  // O^T[d=f*16+quad*4+reg][q=l16]
  float m = -3.0e38f, l = 0.f;
  const bf16x4 one4 = {(bf16_t)1.0f, (bf16_t)1.0f, (bf16_t)1.0f, (bf16_t)1.0f};

  const int kend_blk = qblk * 64 + 64;
  const int kend_w = q0 + 16;

  // ---- prime the register pipeline with tile kt=0 ----
  bf16x8 rK[2], rV[4];
  rK[0] = *(const bf16x8*)(gK);
  rK[1] = *(const bf16x8*)(gK + 8);
#pragma unroll
  for (int j = 0; j < 4; ++j) rV[j] = *(const bf16x8*)(gV + j * 8);

  for (int kt = 0; kt < kend_blk; kt += 64) {
    // ---- commit staged registers to LDS ----
    *(bf16x8*)(Ks + kwK) = rK[0];
    *(bf16x8*)(Ks + kwK + 8) = rK[1];
#pragma unroll
    for (int j = 0; j < 4; ++j) *(bf16x8*)(Vs + kwV + j * 8) = rV[j];
    __syncthreads();

    // ---- prefetch next tile into registers (overlaps compute) ----
    if (kt + 64 < kend_blk) {
      const long ko = (long)(kt + 64) * NPROJ;
      rK[0] = *(const bf16x8*)(gK + ko);
      rK[1] = *(const bf16x8*)(gK + ko + 8);
#pragma unroll
      for (int j = 0; j < 4; ++j)
        rV[j] = *(const bf16x8*)(gV + kt + 64 + j * 8);
    }

    if (kt < kend_w) {
      // ---- S^T = K Q^T : A=K-frag (from LDS), B=Q-frag (regs) ----
      f32x4 s[4];
#pragma unroll
      for (int c = 0; c < 4; ++c) {
        const bf16_t* kr = Ks + (c * 16 + l16) * KSTR;
        bf16x8 ka0 = *(const bf16x8*)(kr + quad * 8);
        bf16x8 ka1 = *(const bf16x8*)(kr + 32 + quad * 8);
        f32x4 z = {};
        z = MFMA32(ka0, aq[0], z);
        z = MFMA32(ka1, aq[1], z);
        s[c] = z;
      }
      // ---- causal mask (diagonal tile only) + in-lane TREE max ----
      if (kt + 63 > q0) {
#pragma unroll
        for (int c = 0; c < 4; ++c)
#pragma unroll
          for (int i = 0; i < 4; ++i) {
            const int key = kt + c * 16 + quad * 4 + i;
            if (key > qg) s[c][i] = -1e30f;
          }
      }
      float t[4];
#pragma unroll
      for (int c = 0; c < 4; ++c)
        t[c] = fmaxf(fmaxf(s[c][0], s[c][1]), fmaxf(s[c][2], s[c][3]));
      float mx = fmaxf(fmaxf(t[0], t[1]), fmaxf(t[2], t[3]));
      mx = fmaxf(mx, __shfl_xor(mx, 16));
      mx = fmaxf(mx, __shfl_xor(mx, 32));
      // ---- defer-rescale (T13) ----
      if (!__all(mx <= m + RTHR)) {
        const float mn = fmaxf(m, mx);
        const float al = exp2f((m - mn) * sc);
        m = mn;
#pragma unroll
        for (int f = 0; f < 8; ++f)
#pragma unroll
          for (int i = 0; i < 4; ++i) O[f][i] *= al;
        l *= al;
      }
      // ---- P = exp2(fma(s,sc,-m*sc)), packed bf16x4 per c ----
      const float ms = m * sc;
      bf16x4 pc[4];
#pragma unroll
      for (int c = 0; c < 4; ++c)
#pragma unroll
        for (int i = 0; i < 4; ++i)
          pc[c][i] = (bf16_t)exp2f(fmaf(s[c][i], sc, -ms));
      // ---- row-sum l via ones-row MFMA ----
      f32x4 la = {};
#pragma unroll
      for (int c = 0; c < 4; ++c) la = MFMA16(one4, pc[c], la);
      // ---- PV: O^T += V^T P^T ----
#pragma unroll
      for (int c = 0; c < 4; ++c) {
#pragma unroll
        for (int f = 0; f < 8; ++f) {
          bf16x4 va =
              *(const bf16x4*)(Vs + (f * 16 + l16) * KSTR + c * 16 + quad * 4);
          O[f] = MFMA16(va, pc[c], O[f]);
        }
      }
      l += la[0];
    }
    __syncthreads();
  }

  // ---- normalize and store per-stream a_s = (P/l)V as fp16 ----
  const float inv = 1.0f / l;
  _Float16* ob = st ? a2 : a1;
  _Float16* dst = ob + ((bT + qg) * 16 + h) * (long)128 + quad * 4;
#pragma unroll
  for (int f = 0; f < 8; ++f) {
    f16x4 o = {(_Float16)(O[f][0] * inv), (_Float16)(O[f][1] * inv),
               (_Float16)(O[f][2] * inv), (_Float16)(O[f][3] * inv)};
    *(f16x4*)(dst + f * 16) = o;
  }
}

// ---------------- combine: y = a1 - lam*a2, subLN(128), *(1-LI) -> bf16 ------
__global__ void __launch_bounds__(256) combine_kernel(const _Float16* __restrict__ a1,
                                                      const _Float16* __restrict__ a2,
                                                      const float* __restrict__ lamp,
                                                      bf16_t* __restrict__ yln) {
  const int unit = blockIdx.x * 4 + (threadIdx.x >> 6);  // 0..65535 = r*16+h
  const int lane = threadIdx.x & 63;
  const float lam = lamp[unit & 15];
  const long base = (long)unit * 128 + lane * 2;
  f16x2 v1 = *(const f16x2*)(a1 + base);
  f16x2 v2 = *(const f16x2*)(a2 + base);
  float y0 = (float)v1[0] - lam * (float)v2[0];
  float y1 = (float)v1[1] - lam * (float)v2[1];
  float sm = y0 + y1, sq = y0 * y0 + y1 * y1;
#pragma unroll
  for (int off = 1; off < 64; off <<= 1) {
    sm += __shfl_xor(sm, off);
    sq += __shfl_xor(sq, off);
  }
  const float mu = sm * (1.0f / 128.0f);
  const float var = sq * (1.0f / 128.0f) - mu * mu;
  const float rs = rsqrtf(var + 1e-5f) * ONE_MINUS_LI;
  bf16x2 o = {(bf16_t)((y0 - mu) * rs), (bf16_t)((y1 - mu) * rs)};
  *(bf16x2*)(yln + base) = o;
}

// ---------------------------------------------------------------------------
extern "C" void kernel_launch(void* const* d_in, const int* in_sizes, int n_in,
                              void* d_out, int out_size, void* d_ws,
                              size_t ws_size, hipStream_t stream) {
  const float* x = (const float*)d_in[0];
  const float* Wq1 = (const float*)d_in[1];
  const float* Wq2 = (const float*)d_in[2];
  const float* Wk1 = (const float*)d_in[3];
  const float* Wk2 = (const float*)d_in[4];
  const float* Wv = (const float*)d_in[5];
  const float* Wc = (const float*)d_in[6];
  const float* lq1 = (const float*)d_in[7];
  const float* lk1 = (const float*)d_in[8];
  const float* lq2 = (const float*)d_in[9];
  const float* lk2 = (const float*)d_in[10];
  float* out = (float*)d_out;

  char* ws = (char*)d_ws;
  bf16_t* wcat = (bf16_t*)(ws + OFF_WCAT);
  bf16_t* xb = (bf16_t*)(ws + OFF_XB);
  bf16_t* wct = (bf16_t*)(ws + OFF_WCT);
  bf16_t* projb = (bf16_t*)(ws + OFF_PROJ);
  bf16_t* vtb = (bf16_t*)(ws + OFF_VT);
  bf16_t* ylnb = (bf16_t*)(ws + OFF_YLN);
  float* lamp = (float*)(ws + OFF_LAM);
  _Float16* a1b = (_Float16*)(ws + OFF_YLN);   // aliases yln (in-place combine)
  _Float16* a2b = (_Float16*)(ws + OFF_WCAT);  // aliases wcat+xb (dead after proj)

  cast_x<<<4096, 256, 0, stream>>>(x, xb);
  tcast_w4<<<dim3(32, 32, 4), 256, 0, stream>>>(Wq1, Wq2, Wk1, Wk2, wcat);
  tcast_w<<<dim3(32, 64), 256, 0, stream>>>(Wv, wcat, 1024, 2048, 4096);
  tcast_w<<<dim3(64, 32), 256, 0, stream>>>(Wc, wct, 2048, 1024, 0);
  lam_kernel<<<1, 64, 0, stream>>>(lq1, lk1, lq2, lk2, lamp);

  // proj = xb @ wcat^T : M=4096 N=6144 K=1024 ; 16x24 = 384 tiles (384%8==0)
  gemm256<<<dim3(384), 512, 0, stream>>>(xb, wcat, projb, 4096, 6144, 1024, 24);
  transpose_v<<<dim3(32, 4, 64), 256, 0, stream>>>(projb, vtb);
  attn_kernel<<<dim3(2048), 256, 0, stream>>>(projb, vtb, a1b, a2b);
  combine_kernel<<<dim3(16384), 256, 0, stream>>>(a1b, a2b, lamp, ylnb);
  // out = yln @ wc^T : M=4096 N=1024 K=2048  (BN=64 -> 512 blocks)
  gemm_bt_n64<float><<<dim3(16, 32), 256, 0, stream>>>(ylnb, wct, out, 4096, 1024, 2048);
}